// Round 14
// baseline (389.809 us; speedup 1.0000x reference)
//
#include <hip/hip_runtime.h>
#include <hip/hip_fp16.h>
#include <stdint.h>

// Problem constants (x: (2,21,256,256) f32, image: (2,3,256,256) f32, bilateral d=5)
#define BB   2
#define CC   21
#define HCP  32              // halves per lattice row (64 B = exactly 1 cache line)
#define NPT  (BB*256*256)    // 131072 points
#define DP1  6
#define NV   (NPT*DP1)       // 786432 point-vertex pairs (max unique keys)
#define TS   (1u<<21)        // hash slots
#define TMASK (TS-1)
#define EMPTYK 0xFFFFFFFFFFFFFFFFULL
#define NBLK (NV/1024)       // 768 scan blocks (pair-count scan)
#define NBUCK 32768          // owner-pixel buckets (pixel id >> 2): dense & uniform
// 41-bit key: 5 coords x 8 bits (coord+128, each byte in [26,230]) + batch bit 40.
// bits 41..63 of the hash word: owner pixel id (insert) then compact idx (place).
#define KEYMASK ((1ULL<<41)-1ULL)

// R7 lesson: do NOT swizzle blockIdx (halved blur BW at equal FETCH).
// R9 lesson: bucket function must be LOAD-UNIFORM first, local second.
// R11/R12: fp16 64B lattice rows -> 1 line per random gather (611 -> 381 us).
// R13: inserts at pair granularity (6x waves) + hslot reuse kills k_find probes.

__device__ __forceinline__ uint64_t hmix(uint64_t x){
  x ^= x >> 33; x *= 0xff51afd7ed558ccdULL;
  x ^= x >> 33; x *= 0xc4ceb9fe1a85ec53ULL;
  x ^= x >> 33; return x;
}

__device__ __forceinline__ int hlookup(const unsigned long long* __restrict__ hs,
                                       uint64_t key){
  uint32_t h = (uint32_t)hmix(key) & TMASK;
  for (;;){
    unsigned long long e = hs[h];
    if (e == EMPTYK) return -1;
    if ((e & KEYMASK) == (unsigned long long)key) return (int)(e >> 41);
    h = (h + 1) & TMASK;
  }
}

// load first 24 halves (3x16B) of a 64B-aligned row -> 12 float2
__device__ __forceinline__ void row_load(const __half* p, float2 f[12]){
  const uint4* p4 = (const uint4*)p;
  #pragma unroll
  for (int i=0;i<3;i++){
    uint4 r = p4[i];
    const __half2* h = (const __half2*)&r;
    #pragma unroll
    for (int j=0;j<4;j++) f[i*4+j] = __half22float2(h[j]);
  }
}
// store 12 float2 -> first 24 halves of a row
__device__ __forceinline__ void row_store(__half* p, const float2 f[12]){
  uint4* p4 = (uint4*)p;
  #pragma unroll
  for (int i=0;i<3;i++){
    uint4 r;
    __half2* h = (__half2*)&r;
    #pragma unroll
    for (int j=0;j<4;j++) h[j] = __floats2half2_rn(f[i*4+j].x, f[i*4+j].y);
    p4[i] = r;
  }
}

// K0: transpose x (NCHW) -> xt (fp16 row-per-pixel, 64 B rows, pads zero)
__global__ __launch_bounds__(256) void k_tx(const float* __restrict__ xin,
      __half* __restrict__ xt){
  int n = blockIdx.x*256 + threadIdx.x;
  if (n >= NPT) return;
  int b = n >> 16, pix = n & 65535;
  const float* xb = xin + (((size_t)b*CC) << 16) + pix;
  float2 v[12];
  #pragma unroll
  for (int q=0;q<12;q++){
    int c0 = 2*q, c1 = 2*q+1;
    v[q].x = (c0 < CC) ? xb[(size_t)c0 << 16] : 0.f;
    v[q].y = (c1 < CC) ? xb[(size_t)c1 << 16] : 0.f;
  }
  row_store(xt + (size_t)n*HCP, v);
}

// K1: per-point lattice math ONLY — streams pkeys/pbary, no hash traffic.
__global__ __launch_bounds__(256) void k_build(const float* __restrict__ img,
      unsigned long long* __restrict__ pkeys,
      float* __restrict__ pbary){
  int n = blockIdx.x*256 + threadIdx.x;
  if (n >= NPT) return;
  int b = n >> 16, pix = n & 65535;
  int y = pix >> 8, x = pix & 255;
  // scale[j] = sqrt(2/3)*6 / sqrt((j+1)(j+2)), as float32 (numpy f64 -> f32)
  const float sc0 = 3.4641016151377544f, sc1 = 2.0f, sc2 = 1.4142135623730951f,
              sc3 = 1.0954451150103321f, sc4 = 0.8944271909999159f;
  size_t ib = ((size_t)b*3) << 16;
  float f0 = ((float)x / 80.0f) * sc0;                      // xs / THETA_ALPHA
  float f1 = ((float)y / 80.0f) * sc1;                      // ys / THETA_ALPHA
  float f2 = (img[ib + pix]          / 13.0f) * sc2;        // R / THETA_BETA
  float f3 = (img[ib + 65536 + pix]  / 13.0f) * sc3;        // G
  float f4 = (img[ib + 131072 + pix] / 13.0f) * sc4;        // B
  // elevate: E rows [1,1,1,1,1],[-1,1,1,1,1],[0,-2,1,1,1],[0,0,-3,1,1],[0,0,0,-4,1],[0,0,0,0,-5]
  float E[6];
  {
    float s4 = f4;
    E[5] = -5.0f*f4;
    E[4] = -4.0f*f3 + s4;
    float s3 = f3 + s4;
    E[3] = -3.0f*f2 + s3;
    float s2 = f2 + s3;
    E[2] = -2.0f*f1 + s2;
    float s1 = f1 + s2;
    E[1] = -f0 + s1;
    E[0] =  f0 + s1;
  }
  float rem0[6], di[6]; int rk[6];
  float ssf = 0.f;
  #pragma unroll
  for (int i=0;i<6;i++){
    float v  = E[i] / 6.0f;
    float up = ceilf(v)*6.0f, dn = floorf(v)*6.0f;
    float r0 = (up - E[i] < E[i] - dn) ? up : dn;
    rem0[i] = r0; di[i] = E[i] - r0; ssf += r0;     // di from PRE-wrap rem0
  }
  int ssum = (int)rintf(ssf / 6.0f);                 // exact: rem0 are multiples of 6
  #pragma unroll
  for (int i=0;i<6;i++){
    int c = ssum;
    #pragma unroll
    for (int k=0;k<6;k++){
      if (k==i) continue;
      bool t = (k>i) ? (di[i] < di[k]) : (di[i] <= di[k]);
      c += t ? 1 : 0;
    }
    rk[i] = c;
  }
  #pragma unroll
  for (int i=0;i<6;i++){
    if      (rk[i] < 0){ rk[i] += 6; rem0[i] += 6.0f; }
    else if (rk[i] > 5){ rk[i] -= 6; rem0[i] -= 6.0f; }
  }
  // barycentric: bar[5-rk] += t; bar[6-rk] -= t  (unrolled to keep in registers)
  float bar[7] = {0,0,0,0,0,0,0};
  #pragma unroll
  for (int i=0;i<6;i++){
    float t = (E[i] - rem0[i]) / 6.0f;               // t from POST-wrap rem0
    #pragma unroll
    for (int j=0;j<7;j++){
      bar[j] += ((5-rk[i])==j) ? t : 0.0f;
      bar[j] -= ((6-rk[i])==j) ? t : 0.0f;
    }
  }
  float w0 = bar[0] + 1.0f + bar[6];
  int ri[5];
  #pragma unroll
  for (int i=0;i<5;i++) ri[i] = (int)rintf(rem0[i]);
  uint64_t bbit = ((uint64_t)b) << 40;
  #pragma unroll
  for (int r=0;r<6;r++){
    uint64_t key = bbit;
    #pragma unroll
    for (int i=0;i<5;i++){
      int k = ri[i] + r - ((rk[i] > 5-r) ? 6 : 0);   // |k| <= 102 -> +128 in [26,230]
      key |= ((uint64_t)(uint32_t)(k + 128) & 0xFFULL) << (8*i);
    }
    pkeys[n*6+r] = key;
    pbary[n*6+r] = (r==0) ? w0 : bar[r];
  }
}

// K1b: one insert per PAIR (6x wave parallelism vs per-point). Records the
// landing slot in hslot[t]; CAS winner embeds owner pixel + counts its bucket.
__global__ __launch_bounds__(256) void k_insert(const unsigned long long* __restrict__ pkeys,
      unsigned long long* __restrict__ hs, int* __restrict__ hist,
      int* __restrict__ hslot){
  int t = blockIdx.x*256 + threadIdx.x;
  if (t >= NV) return;
  uint64_t key = (uint64_t)pkeys[t];
  uint32_t n = (uint32_t)(t / 6);
  uint64_t ins = key | ((uint64_t)n << 41);
  uint32_t h = (uint32_t)hmix(key) & TMASK;
  for (;;){
    unsigned long long seen = hs[h];
    if (seen != EMPTYK && (seen & KEYMASK) == (unsigned long long)key) break;
    if (seen == EMPTYK){
      unsigned long long prev = atomicCAS(&hs[h], EMPTYK, (unsigned long long)ins);
      if (prev == EMPTYK){
        atomicAdd(&hist[n >> 2], 1);   // fire-and-forget bucket count
        break;
      }
      if ((prev & KEYMASK) == (unsigned long long)key) break;
    }
    h = (h + 1) & TMASK;
  }
  hslot[t] = (int)h;
}

// K2b: single-block scan of NBUCK bucket counts (32 serial buckets per thread)
__global__ __launch_bounds__(1024) void k_scan_small(const int* __restrict__ hist,
      int* __restrict__ boff, int* __restrict__ bcur, int* __restrict__ counter){
  __shared__ int s[1024];
  int t = threadIdx.x;
  int base = t * (NBUCK/1024);
  int loc[NBUCK/1024];
  int sum = 0;
  #pragma unroll
  for (int i=0;i<NBUCK/1024;i++){ loc[i] = hist[base+i]; sum += loc[i]; }
  s[t] = sum;
  __syncthreads();
  #pragma unroll
  for (int o=1;o<1024;o<<=1){
    int add = (t>=o) ? s[t-o] : 0;
    __syncthreads();
    s[t] += add;
    __syncthreads();
  }
  int run = s[t] - sum;   // exclusive prefix for this thread's range
  #pragma unroll
  for (int i=0;i<NBUCK/1024;i++){ boff[base+i] = run; bcur[base+i] = run; run += loc[i]; }
  if (t == 1023) counter[0] = run;
}

// K2c: place occupied slots -> owner-bucket-ordered compact idx.
// Slot positions never move; only bits 41+ change owner->idx.
__global__ __launch_bounds__(1024) void k_place(unsigned long long* __restrict__ hs,
      int* __restrict__ bcur,
      unsigned long long* __restrict__ latkeys){
  uint32_t s = blockIdx.x*1024 + threadIdx.x;
  unsigned long long e = hs[s];
  if (e == EMPTYK) return;
  int nown = (int)(e >> 41);
  int idx = atomicAdd(&bcur[nown >> 2], 1);
  unsigned long long key = e & KEYMASK;
  hs[s] = key | ((unsigned long long)idx << 41);
  latkeys[idx] = key;
}

// K2d: precompute blur neighbor indices — 12 independent probes per vertex, ONCE.
__global__ __launch_bounds__(256) void k_nbr(const unsigned long long* __restrict__ hs,
      const unsigned long long* __restrict__ latkeys, const int* __restrict__ counter,
      uint2* __restrict__ nbr){
  int m = blockIdx.x*256 + threadIdx.x;
  if (m >= *counter) return;
  uint64_t key = (uint64_t)latkeys[m];
  const unsigned long long S5 = (1ULL<<32)+(1ULL<<24)+(1ULL<<16)+(1ULL<<8)+1ULL;
  #pragma unroll
  for (int j=0;j<6;j++){
    unsigned long long delta = (j<5) ? (S5 - (6ULL << (8*j))) : S5;
    int i1 = hlookup(hs, key + delta);
    int i2 = hlookup(hs, key - delta);
    nbr[(size_t)j*NV + m] = make_uint2((uint32_t)(i1+1), (uint32_t)(i2+1));
  }
}

// K3: pidx via recorded slot — ONE random 8B read, no probe chain.
__global__ __launch_bounds__(256) void k_find(const unsigned long long* __restrict__ hs,
      const int* __restrict__ hslot,
      int* __restrict__ pidx, int* __restrict__ cnt){
  int t = blockIdx.x*256 + threadIdx.x;
  if (t >= NV) return;
  int i = (int)(hs[hslot[t]] >> 41);
  pidx[t] = i;
  atomicAdd(&cnt[i], 1);
}

// Scan stage 1
__global__ __launch_bounds__(1024) void k_scan1(const int* __restrict__ cnt,
      int* __restrict__ off, int* __restrict__ bsum){
  __shared__ int s[1024];
  int t = threadIdx.x;
  int i = blockIdx.x*1024 + t;
  int v = cnt[i];
  s[t] = v;
  __syncthreads();
  #pragma unroll
  for (int o=1;o<1024;o<<=1){
    int add = (t>=o) ? s[t-o] : 0;
    __syncthreads();
    s[t] += add;
    __syncthreads();
  }
  off[i] = s[t] - v;
  if (t==1023) bsum[blockIdx.x] = s[t];
}

// Scan stage 2
__global__ __launch_bounds__(1024) void k_scan2(int* __restrict__ bsum){
  __shared__ int s[1024];
  int t = threadIdx.x;
  int v = (t < NBLK) ? bsum[t] : 0;
  s[t] = v;
  __syncthreads();
  #pragma unroll
  for (int o=1;o<1024;o<<=1){
    int add = (t>=o) ? s[t-o] : 0;
    __syncthreads();
    s[t] += add;
    __syncthreads();
  }
  if (t < NBLK) bsum[t] = s[t] - v;
}

// Scan stage 3
__global__ __launch_bounds__(1024) void k_scan3(int* __restrict__ off,
      const int* __restrict__ bsum, int* __restrict__ cur){
  int i = blockIdx.x*1024 + threadIdx.x;
  int o = off[i] + bsum[blockIdx.x];
  off[i] = o;
  cur[i] = o;
}

// K4a: scatter {pixel id, weight} into CSR pairlist
__global__ __launch_bounds__(256) void k_scatter(const int* __restrict__ pidx,
      const float* __restrict__ pbary, int* __restrict__ cur, uint2* __restrict__ plist2){
  int t = blockIdx.x*256 + threadIdx.x;
  if (t >= NV) return;
  int idx = pidx[t];
  int pos = atomicAdd(&cur[idx], 1);
  plist2[pos] = make_uint2((uint32_t)(t/6), __float_as_uint(pbary[t]));
}

// K4b: gather-reduce splat — fp16 xt rows (1 line/gather), fp32 acc, fp16 store
__global__ __launch_bounds__(256) void k_splat2(const __half* __restrict__ xt,
      const int* __restrict__ off, const int* __restrict__ cnt,
      const uint2* __restrict__ plist2, const int* __restrict__ counter,
      __half* __restrict__ lat){
  int m = blockIdx.x*256 + threadIdx.x;
  if (m >= *counter) return;
  float2 acc[12];
  #pragma unroll
  for (int q=0;q<12;q++) acc[q] = make_float2(0.f,0.f);
  int c0 = off[m], k = cnt[m];
  for (int e=c0; e<c0+k; ++e){
    uint2 pv = plist2[e];
    float w = __uint_as_float(pv.y);
    float2 xr[12];
    row_load(xt + (size_t)pv.x*HCP, xr);
    #pragma unroll
    for (int q=0;q<12;q++){
      acc[q].x = fmaf(w, xr[q].x, acc[q].x);
      acc[q].y = fmaf(w, xr[q].y, acc[q].y);
    }
  }
  row_store(lat + (size_t)m*HCP, acc);
}

// K5: one blur direction via precomputed neighbor list; fp32 math, fp16 rows
__global__ __launch_bounds__(256) void k_blur(const uint2* __restrict__ nbrj,
      const int* __restrict__ counter, const __half* __restrict__ src,
      __half* __restrict__ dst){
  int m = blockIdx.x*256 + threadIdx.x;
  if (m >= *counter) return;
  uint2 e = nbrj[m];
  float2 a[12], u[12], v[12];
  #pragma unroll
  for (int q=0;q<12;q++){ u[q] = make_float2(0.f,0.f); v[q] = make_float2(0.f,0.f); }
  row_load(src + (size_t)m*HCP, a);
  if (e.x) row_load(src + (size_t)(e.x-1u)*HCP, u);
  if (e.y) row_load(src + (size_t)(e.y-1u)*HCP, v);
  float2 r[12];
  #pragma unroll
  for (int q=0;q<12;q++){
    r[q].x = a[q].x + 0.5f*(u[q].x + v[q].x);
    r[q].y = a[q].y + 0.5f*(u[q].y + v[q].y);
  }
  row_store(dst + (size_t)m*HCP, r);
}

// K6: slice — out[b,c,y,x] = alpha * sum_r bary[r] * lat[idx[r]][c]
__global__ __launch_bounds__(256) void k_slice(const __half* __restrict__ lat,
      const int* __restrict__ pidx, const float* __restrict__ pbary,
      float* __restrict__ out){
  int n = blockIdx.x*256 + threadIdx.x;
  if (n >= NPT) return;
  float2 acc[12];
  #pragma unroll
  for (int q=0;q<12;q++) acc[q] = make_float2(0.f,0.f);
  #pragma unroll
  for (int r=0;r<6;r++){
    int idx = pidx[n*6+r]; float w = pbary[n*6+r];
    float2 L[12];
    row_load(lat + (size_t)idx*HCP, L);
    #pragma unroll
    for (int q=0;q<12;q++){
      acc[q].x = fmaf(w, L[q].x, acc[q].x);
      acc[q].y = fmaf(w, L[q].y, acc[q].y);
    }
  }
  int b = n >> 16, pix = n & 65535;
  float* ob = out + (((size_t)b*CC) << 16) + pix;
  const float alpha = 0.9696969696969697f;  // 1/(1+2^-5) = 32/33
  #pragma unroll
  for (int c=0;c<CC;c++){
    float val = (c & 1) ? acc[c>>1].y : acc[c>>1].x;
    ob[(size_t)c << 16] = alpha * val;
  }
}

extern "C" void kernel_launch(void* const* d_in, const int* in_sizes, int n_in,
                              void* d_out, int out_size, void* d_ws, size_t ws_size,
                              hipStream_t stream){
  const float* xin = (const float*)d_in[0];   // (2,21,256,256)
  const float* img = (const float*)d_in[1];   // (2,3,256,256)
  float* out = (float*)d_out;                 // (2,21,256,256)

  // workspace carve (each region 256B-aligned); total ~188 MB
  char* p = (char*)d_ws;
  auto carve = [&](size_t bytes)->char*{
    char* r = p; p += (bytes + 255) & ~(size_t)255; return r;
  };
  unsigned long long* hs      = (unsigned long long*)carve((size_t)TS*8);   // 16.8 MB
  unsigned long long* latkeys = (unsigned long long*)carve((size_t)NV*8);   //  6.3 MB
  int*                counter = (int*)               carve(256);
  unsigned long long* pkeys   = (unsigned long long*)carve((size_t)NV*8);   //  6.3 MB
  int*                pidx    = (int*)               carve((size_t)NV*4);   //  3.1 MB
  float*              pbary   = (float*)             carve((size_t)NV*4);   //  3.1 MB
  int*                hslot   = (int*)               carve((size_t)NV*4);   //  3.1 MB
  int*                cnt     = (int*)               carve((size_t)NV*4);   //  3.1 MB
  int*                off     = (int*)               carve((size_t)NV*4);   //  3.1 MB
  int*                cur     = (int*)               carve((size_t)NV*4);   //  3.1 MB
  int*                bsum    = (int*)               carve((size_t)NBLK*4); //  3 KB
  int*                hist    = (int*)               carve((size_t)NBUCK*4);// 128 KB
  int*                boff    = (int*)               carve((size_t)NBUCK*4);// 128 KB
  int*                bcur    = (int*)               carve((size_t)NBUCK*4);// 128 KB
  uint2*              nbr     = (uint2*)             carve((size_t)6*NV*8); // 37.7 MB
  __half*             latA    = (__half*)            carve((size_t)NV*HCP*2);// 48.2 MB
  __half*             latB    = (__half*)            carve((size_t)NV*HCP*2);// 48.2 MB

  // aliases (non-overlapping liveness):
  //   xt (fp16, NPT*64B = 8.4 MB) lives in latB — dead before blur j=0 writes latB
  //   plist2 reuses pkeys — pkeys dead after k_insert
  __half* xt     = latB;
  uint2* plist2  = (uint2*)pkeys;

  hipMemsetAsync(hs, 0xFF, (size_t)TS*8, stream);
  hipMemsetAsync(cnt, 0, (size_t)NV*4, stream);
  hipMemsetAsync(hist, 0, (size_t)NBUCK*4, stream);

  k_tx        <<<NPT/256, 256, 0, stream>>>(xin, xt);
  k_build     <<<NPT/256, 256, 0, stream>>>(img, pkeys, pbary);
  k_insert    <<<NV/256,  256, 0, stream>>>(pkeys, hs, hist, hslot);
  k_scan_small<<<1,      1024, 0, stream>>>(hist, boff, bcur, counter);
  k_place     <<<TS/1024,1024, 0, stream>>>(hs, bcur, latkeys);
  k_nbr       <<<NV/256,  256, 0, stream>>>(hs, latkeys, counter, nbr);
  k_find      <<<NV/256,  256, 0, stream>>>(hs, hslot, pidx, cnt);
  k_scan1     <<<NBLK,   1024, 0, stream>>>(cnt, off, bsum);
  k_scan2     <<<1,      1024, 0, stream>>>(bsum);
  k_scan3     <<<NBLK,   1024, 0, stream>>>(off, bsum, cur);
  k_scatter   <<<NV/256,  256, 0, stream>>>(pidx, pbary, cur, plist2);
  k_splat2    <<<NV/256,  256, 0, stream>>>(xt, off, cnt, plist2, counter, latA);

  // 6 blur passes, ping-pong latA <-> latB, using precomputed neighbor lists
  __half* src = latA; __half* dst = latB;
  for (int j=0;j<6;j++){
    k_blur<<<NV/256, 256, 0, stream>>>(nbr + (size_t)j*NV, counter, src, dst);
    __half* tmp = src; src = dst; dst = tmp;
  }
  // after 6 swaps src == latA (final)
  k_slice<<<NPT/256, 256, 0, stream>>>(src, pidx, pbary, out);
}

// Round 15
// 372.565 us; speedup vs baseline: 1.0463x; 1.0463x over previous
//
#include <hip/hip_runtime.h>
#include <hip/hip_fp16.h>
#include <stdint.h>

// Problem constants (x: (2,21,256,256) f32, image: (2,3,256,256) f32, bilateral d=5)
#define BB   2
#define CC   21
#define HCP  32              // halves per lattice row (64 B = exactly 1 cache line)
#define NPT  (BB*256*256)    // 131072 points
#define DP1  6
#define NV   (NPT*DP1)       // 786432 point-vertex pairs (max unique keys)
#define TS   (1u<<20)        // hash slots (load ~52% — R14: halved for L2 hit rate)
#define TMASK (TS-1)
#define EMPTYK 0xFFFFFFFFFFFFFFFFULL
#define NBLK (NV/1024)       // 768 scan blocks (pair-count scan)
#define NBUCK 32768          // owner-pixel buckets (pixel id >> 2): dense & uniform
// 41-bit key: 5 coords x 8 bits (coord+128, each byte in [26,230]) + batch bit 40.
// bits 41..63 of the hash word: owner pixel id (build) then compact idx (place).
#define KEYMASK ((1ULL<<41)-1ULL)

// R7: do NOT swizzle blockIdx. R9: buckets must be load-uniform.
// R11/R12: fp16 64B lattice rows -> 1 line per random gather (611 -> 381 us).
// R13 lesson: insert is random-RMW-throughput-bound, NOT latency-bound — more
// waves don't help; keep per-point insert but record hslot for probe-free find.

__device__ __forceinline__ uint64_t hmix(uint64_t x){
  x ^= x >> 33; x *= 0xff51afd7ed558ccdULL;
  x ^= x >> 33; x *= 0xc4ceb9fe1a85ec53ULL;
  x ^= x >> 33; return x;
}

__device__ __forceinline__ int hlookup(const unsigned long long* __restrict__ hs,
                                       uint64_t key){
  uint32_t h = (uint32_t)hmix(key) & TMASK;
  for (;;){
    unsigned long long e = hs[h];
    if (e == EMPTYK) return -1;
    if ((e & KEYMASK) == (unsigned long long)key) return (int)(e >> 41);
    h = (h + 1) & TMASK;
  }
}

// load first 24 halves (3x16B) of a 64B-aligned row -> 12 float2
__device__ __forceinline__ void row_load(const __half* p, float2 f[12]){
  const uint4* p4 = (const uint4*)p;
  #pragma unroll
  for (int i=0;i<3;i++){
    uint4 r = p4[i];
    const __half2* h = (const __half2*)&r;
    #pragma unroll
    for (int j=0;j<4;j++) f[i*4+j] = __half22float2(h[j]);
  }
}
// store 12 float2 -> first 24 halves of a row
__device__ __forceinline__ void row_store(__half* p, const float2 f[12]){
  uint4* p4 = (uint4*)p;
  #pragma unroll
  for (int i=0;i<3;i++){
    uint4 r;
    __half2* h = (__half2*)&r;
    #pragma unroll
    for (int j=0;j<4;j++) h[j] = __floats2half2_rn(f[i*4+j].x, f[i*4+j].y);
    p4[i] = r;
  }
}

// K0: transpose x (NCHW) -> xt (fp16 row-per-pixel, 64 B rows, pads zero)
__global__ __launch_bounds__(256) void k_tx(const float* __restrict__ xin,
      __half* __restrict__ xt){
  int n = blockIdx.x*256 + threadIdx.x;
  if (n >= NPT) return;
  int b = n >> 16, pix = n & 65535;
  const float* xb = xin + (((size_t)b*CC) << 16) + pix;
  float2 v[12];
  #pragma unroll
  for (int q=0;q<12;q++){
    int c0 = 2*q, c1 = 2*q+1;
    v[q].x = (c0 < CC) ? xb[(size_t)c0 << 16] : 0.f;
    v[q].y = (c1 < CC) ? xb[(size_t)c1 << 16] : 0.f;
  }
  row_store(xt + (size_t)n*HCP, v);
}

// K1: per-point lattice math + hash insert (owner embedded in CAS value) +
// hslot recording for probe-free k_find.
__global__ __launch_bounds__(256) void k_build(const float* __restrict__ img,
      unsigned long long* __restrict__ hs,
      int* __restrict__ hist,
      unsigned long long* __restrict__ pkeys,
      float* __restrict__ pbary,
      int* __restrict__ hslot){
  int n = blockIdx.x*256 + threadIdx.x;
  if (n >= NPT) return;
  int b = n >> 16, pix = n & 65535;
  int y = pix >> 8, x = pix & 255;
  // scale[j] = sqrt(2/3)*6 / sqrt((j+1)(j+2)), as float32 (numpy f64 -> f32)
  const float sc0 = 3.4641016151377544f, sc1 = 2.0f, sc2 = 1.4142135623730951f,
              sc3 = 1.0954451150103321f, sc4 = 0.8944271909999159f;
  size_t ib = ((size_t)b*3) << 16;
  float f0 = ((float)x / 80.0f) * sc0;                      // xs / THETA_ALPHA
  float f1 = ((float)y / 80.0f) * sc1;                      // ys / THETA_ALPHA
  float f2 = (img[ib + pix]          / 13.0f) * sc2;        // R / THETA_BETA
  float f3 = (img[ib + 65536 + pix]  / 13.0f) * sc3;        // G
  float f4 = (img[ib + 131072 + pix] / 13.0f) * sc4;        // B
  // elevate: E rows [1,1,1,1,1],[-1,1,1,1,1],[0,-2,1,1,1],[0,0,-3,1,1],[0,0,0,-4,1],[0,0,0,0,-5]
  float E[6];
  {
    float s4 = f4;
    E[5] = -5.0f*f4;
    E[4] = -4.0f*f3 + s4;
    float s3 = f3 + s4;
    E[3] = -3.0f*f2 + s3;
    float s2 = f2 + s3;
    E[2] = -2.0f*f1 + s2;
    float s1 = f1 + s2;
    E[1] = -f0 + s1;
    E[0] =  f0 + s1;
  }
  float rem0[6], di[6]; int rk[6];
  float ssf = 0.f;
  #pragma unroll
  for (int i=0;i<6;i++){
    float v  = E[i] / 6.0f;
    float up = ceilf(v)*6.0f, dn = floorf(v)*6.0f;
    float r0 = (up - E[i] < E[i] - dn) ? up : dn;
    rem0[i] = r0; di[i] = E[i] - r0; ssf += r0;     // di from PRE-wrap rem0
  }
  int ssum = (int)rintf(ssf / 6.0f);                 // exact: rem0 are multiples of 6
  #pragma unroll
  for (int i=0;i<6;i++){
    int c = ssum;
    #pragma unroll
    for (int k=0;k<6;k++){
      if (k==i) continue;
      bool t = (k>i) ? (di[i] < di[k]) : (di[i] <= di[k]);
      c += t ? 1 : 0;
    }
    rk[i] = c;
  }
  #pragma unroll
  for (int i=0;i<6;i++){
    if      (rk[i] < 0){ rk[i] += 6; rem0[i] += 6.0f; }
    else if (rk[i] > 5){ rk[i] -= 6; rem0[i] -= 6.0f; }
  }
  // barycentric: bar[5-rk] += t; bar[6-rk] -= t  (unrolled to keep in registers)
  float bar[7] = {0,0,0,0,0,0,0};
  #pragma unroll
  for (int i=0;i<6;i++){
    float t = (E[i] - rem0[i]) / 6.0f;               // t from POST-wrap rem0
    #pragma unroll
    for (int j=0;j<7;j++){
      bar[j] += ((5-rk[i])==j) ? t : 0.0f;
      bar[j] -= ((6-rk[i])==j) ? t : 0.0f;
    }
  }
  float w0 = bar[0] + 1.0f + bar[6];
  int ri[5];
  #pragma unroll
  for (int i=0;i<5;i++) ri[i] = (int)rintf(rem0[i]);
  uint64_t bbit = ((uint64_t)b) << 40;
  #pragma unroll
  for (int r=0;r<6;r++){
    uint64_t key = bbit;
    #pragma unroll
    for (int i=0;i<5;i++){
      int k = ri[i] + r - ((rk[i] > 5-r) ? 6 : 0);   // |k| <= 102 -> +128 in [26,230]
      key |= ((uint64_t)(uint32_t)(k + 128) & 0xFFULL) << (8*i);
    }
    pkeys[n*6+r] = key;
    pbary[n*6+r] = (r==0) ? w0 : bar[r];
    uint64_t ins = key | ((uint64_t)(uint32_t)n << 41);   // owner embedded
    uint32_t h = (uint32_t)hmix(key) & TMASK;
    for (;;){
      unsigned long long seen = hs[h];
      if (seen != EMPTYK && (seen & KEYMASK) == (unsigned long long)key) break;
      if (seen == EMPTYK){
        unsigned long long prev = atomicCAS(&hs[h], EMPTYK, (unsigned long long)ins);
        if (prev == EMPTYK){
          atomicAdd(&hist[n >> 2], 1);   // fire-and-forget bucket count
          break;
        }
        if ((prev & KEYMASK) == (unsigned long long)key) break;
      }
      h = (h + 1) & TMASK;
    }
    hslot[n*6+r] = (int)h;
  }
}

// K2b: single-block scan of NBUCK bucket counts (32 serial buckets per thread)
__global__ __launch_bounds__(1024) void k_scan_small(const int* __restrict__ hist,
      int* __restrict__ boff, int* __restrict__ bcur, int* __restrict__ counter){
  __shared__ int s[1024];
  int t = threadIdx.x;
  int base = t * (NBUCK/1024);
  int loc[NBUCK/1024];
  int sum = 0;
  #pragma unroll
  for (int i=0;i<NBUCK/1024;i++){ loc[i] = hist[base+i]; sum += loc[i]; }
  s[t] = sum;
  __syncthreads();
  #pragma unroll
  for (int o=1;o<1024;o<<=1){
    int add = (t>=o) ? s[t-o] : 0;
    __syncthreads();
    s[t] += add;
    __syncthreads();
  }
  int run = s[t] - sum;   // exclusive prefix for this thread's range
  #pragma unroll
  for (int i=0;i<NBUCK/1024;i++){ boff[base+i] = run; bcur[base+i] = run; run += loc[i]; }
  if (t == 1023) counter[0] = run;
}

// K2c: place occupied slots -> owner-bucket-ordered compact idx.
// Slot positions never move; only bits 41+ change owner->idx.
__global__ __launch_bounds__(1024) void k_place(unsigned long long* __restrict__ hs,
      int* __restrict__ bcur,
      unsigned long long* __restrict__ latkeys){
  uint32_t s = blockIdx.x*1024 + threadIdx.x;
  unsigned long long e = hs[s];
  if (e == EMPTYK) return;
  int nown = (int)(e >> 41);
  int idx = atomicAdd(&bcur[nown >> 2], 1);
  unsigned long long key = e & KEYMASK;
  hs[s] = key | ((unsigned long long)idx << 41);
  latkeys[idx] = key;
}

// K2d: precompute blur neighbor indices — 12 independent probes per vertex, ONCE.
__global__ __launch_bounds__(256) void k_nbr(const unsigned long long* __restrict__ hs,
      const unsigned long long* __restrict__ latkeys, const int* __restrict__ counter,
      uint2* __restrict__ nbr){
  int m = blockIdx.x*256 + threadIdx.x;
  if (m >= *counter) return;
  uint64_t key = (uint64_t)latkeys[m];
  const unsigned long long S5 = (1ULL<<32)+(1ULL<<24)+(1ULL<<16)+(1ULL<<8)+1ULL;
  #pragma unroll
  for (int j=0;j<6;j++){
    unsigned long long delta = (j<5) ? (S5 - (6ULL << (8*j))) : S5;
    int i1 = hlookup(hs, key + delta);
    int i2 = hlookup(hs, key - delta);
    nbr[(size_t)j*NV + m] = make_uint2((uint32_t)(i1+1), (uint32_t)(i2+1));
  }
}

// K3: pidx via recorded slot — ONE random 8B read, no probe chain.
__global__ __launch_bounds__(256) void k_find(const unsigned long long* __restrict__ hs,
      const int* __restrict__ hslot,
      int* __restrict__ pidx, int* __restrict__ cnt){
  int t = blockIdx.x*256 + threadIdx.x;
  if (t >= NV) return;
  int i = (int)(hs[hslot[t]] >> 41);
  pidx[t] = i;
  atomicAdd(&cnt[i], 1);
}

// Scan stage 1
__global__ __launch_bounds__(1024) void k_scan1(const int* __restrict__ cnt,
      int* __restrict__ off, int* __restrict__ bsum){
  __shared__ int s[1024];
  int t = threadIdx.x;
  int i = blockIdx.x*1024 + t;
  int v = cnt[i];
  s[t] = v;
  __syncthreads();
  #pragma unroll
  for (int o=1;o<1024;o<<=1){
    int add = (t>=o) ? s[t-o] : 0;
    __syncthreads();
    s[t] += add;
    __syncthreads();
  }
  off[i] = s[t] - v;
  if (t==1023) bsum[blockIdx.x] = s[t];
}

// Scan stage 2
__global__ __launch_bounds__(1024) void k_scan2(int* __restrict__ bsum){
  __shared__ int s[1024];
  int t = threadIdx.x;
  int v = (t < NBLK) ? bsum[t] : 0;
  s[t] = v;
  __syncthreads();
  #pragma unroll
  for (int o=1;o<1024;o<<=1){
    int add = (t>=o) ? s[t-o] : 0;
    __syncthreads();
    s[t] += add;
    __syncthreads();
  }
  if (t < NBLK) bsum[t] = s[t] - v;
}

// Scan stage 3
__global__ __launch_bounds__(1024) void k_scan3(int* __restrict__ off,
      const int* __restrict__ bsum, int* __restrict__ cur){
  int i = blockIdx.x*1024 + threadIdx.x;
  int o = off[i] + bsum[blockIdx.x];
  off[i] = o;
  cur[i] = o;
}

// K4a: scatter {pixel id, weight} into CSR pairlist
__global__ __launch_bounds__(256) void k_scatter(const int* __restrict__ pidx,
      const float* __restrict__ pbary, int* __restrict__ cur, uint2* __restrict__ plist2){
  int t = blockIdx.x*256 + threadIdx.x;
  if (t >= NV) return;
  int idx = pidx[t];
  int pos = atomicAdd(&cur[idx], 1);
  plist2[pos] = make_uint2((uint32_t)(t/6), __float_as_uint(pbary[t]));
}

// K4b: gather-reduce splat — fp16 xt rows (1 line/gather), fp32 acc, fp16 store
__global__ __launch_bounds__(256) void k_splat2(const __half* __restrict__ xt,
      const int* __restrict__ off, const int* __restrict__ cnt,
      const uint2* __restrict__ plist2, const int* __restrict__ counter,
      __half* __restrict__ lat){
  int m = blockIdx.x*256 + threadIdx.x;
  if (m >= *counter) return;
  float2 acc[12];
  #pragma unroll
  for (int q=0;q<12;q++) acc[q] = make_float2(0.f,0.f);
  int c0 = off[m], k = cnt[m];
  for (int e=c0; e<c0+k; ++e){
    uint2 pv = plist2[e];
    float w = __uint_as_float(pv.y);
    float2 xr[12];
    row_load(xt + (size_t)pv.x*HCP, xr);
    #pragma unroll
    for (int q=0;q<12;q++){
      acc[q].x = fmaf(w, xr[q].x, acc[q].x);
      acc[q].y = fmaf(w, xr[q].y, acc[q].y);
    }
  }
  row_store(lat + (size_t)m*HCP, acc);
}

// K5: one blur direction via precomputed neighbor list; fp32 math, fp16 rows
__global__ __launch_bounds__(256) void k_blur(const uint2* __restrict__ nbrj,
      const int* __restrict__ counter, const __half* __restrict__ src,
      __half* __restrict__ dst){
  int m = blockIdx.x*256 + threadIdx.x;
  if (m >= *counter) return;
  uint2 e = nbrj[m];
  float2 a[12], u[12], v[12];
  #pragma unroll
  for (int q=0;q<12;q++){ u[q] = make_float2(0.f,0.f); v[q] = make_float2(0.f,0.f); }
  row_load(src + (size_t)m*HCP, a);
  if (e.x) row_load(src + (size_t)(e.x-1u)*HCP, u);
  if (e.y) row_load(src + (size_t)(e.y-1u)*HCP, v);
  float2 r[12];
  #pragma unroll
  for (int q=0;q<12;q++){
    r[q].x = a[q].x + 0.5f*(u[q].x + v[q].x);
    r[q].y = a[q].y + 0.5f*(u[q].y + v[q].y);
  }
  row_store(dst + (size_t)m*HCP, r);
}

// K6: slice — out[b,c,y,x] = alpha * sum_r bary[r] * lat[idx[r]][c]
__global__ __launch_bounds__(256) void k_slice(const __half* __restrict__ lat,
      const int* __restrict__ pidx, const float* __restrict__ pbary,
      float* __restrict__ out){
  int n = blockIdx.x*256 + threadIdx.x;
  if (n >= NPT) return;
  float2 acc[12];
  #pragma unroll
  for (int q=0;q<12;q++) acc[q] = make_float2(0.f,0.f);
  #pragma unroll
  for (int r=0;r<6;r++){
    int idx = pidx[n*6+r]; float w = pbary[n*6+r];
    float2 L[12];
    row_load(lat + (size_t)idx*HCP, L);
    #pragma unroll
    for (int q=0;q<12;q++){
      acc[q].x = fmaf(w, L[q].x, acc[q].x);
      acc[q].y = fmaf(w, L[q].y, acc[q].y);
    }
  }
  int b = n >> 16, pix = n & 65535;
  float* ob = out + (((size_t)b*CC) << 16) + pix;
  const float alpha = 0.9696969696969697f;  // 1/(1+2^-5) = 32/33
  #pragma unroll
  for (int c=0;c<CC;c++){
    float val = (c & 1) ? acc[c>>1].y : acc[c>>1].x;
    ob[(size_t)c << 16] = alpha * val;
  }
}

extern "C" void kernel_launch(void* const* d_in, const int* in_sizes, int n_in,
                              void* d_out, int out_size, void* d_ws, size_t ws_size,
                              hipStream_t stream){
  const float* xin = (const float*)d_in[0];   // (2,21,256,256)
  const float* img = (const float*)d_in[1];   // (2,3,256,256)
  float* out = (float*)d_out;                 // (2,21,256,256)

  // workspace carve (each region 256B-aligned); total ~180 MB
  char* p = (char*)d_ws;
  auto carve = [&](size_t bytes)->char*{
    char* r = p; p += (bytes + 255) & ~(size_t)255; return r;
  };
  unsigned long long* hs      = (unsigned long long*)carve((size_t)TS*8);   //  8.4 MB
  unsigned long long* latkeys = (unsigned long long*)carve((size_t)NV*8);   //  6.3 MB
  int*                counter = (int*)               carve(256);
  unsigned long long* pkeys   = (unsigned long long*)carve((size_t)NV*8);   //  6.3 MB
  int*                pidx    = (int*)               carve((size_t)NV*4);   //  3.1 MB
  float*              pbary   = (float*)             carve((size_t)NV*4);   //  3.1 MB
  int*                hslot   = (int*)               carve((size_t)NV*4);   //  3.1 MB
  int*                cnt     = (int*)               carve((size_t)NV*4);   //  3.1 MB
  int*                off     = (int*)               carve((size_t)NV*4);   //  3.1 MB
  int*                cur     = (int*)               carve((size_t)NV*4);   //  3.1 MB
  int*                bsum    = (int*)               carve((size_t)NBLK*4); //  3 KB
  int*                hist    = (int*)               carve((size_t)NBUCK*4);// 128 KB
  int*                boff    = (int*)               carve((size_t)NBUCK*4);// 128 KB
  int*                bcur    = (int*)               carve((size_t)NBUCK*4);// 128 KB
  uint2*              nbr     = (uint2*)             carve((size_t)6*NV*8); // 37.7 MB
  __half*             latA    = (__half*)            carve((size_t)NV*HCP*2);// 48.2 MB
  __half*             latB    = (__half*)            carve((size_t)NV*HCP*2);// 48.2 MB

  // aliases (non-overlapping liveness):
  //   xt (fp16, NPT*64B = 8.4 MB) lives in latB — dead before blur j=0 writes latB
  //   plist2 reuses pkeys — pkeys dead after k_build
  __half* xt     = latB;
  uint2* plist2  = (uint2*)pkeys;

  hipMemsetAsync(hs, 0xFF, (size_t)TS*8, stream);
  hipMemsetAsync(cnt, 0, (size_t)NV*4, stream);
  hipMemsetAsync(hist, 0, (size_t)NBUCK*4, stream);

  k_tx        <<<NPT/256, 256, 0, stream>>>(xin, xt);
  k_build     <<<NPT/256, 256, 0, stream>>>(img, hs, hist, pkeys, pbary, hslot);
  k_scan_small<<<1,      1024, 0, stream>>>(hist, boff, bcur, counter);
  k_place     <<<TS/1024,1024, 0, stream>>>(hs, bcur, latkeys);
  k_nbr       <<<NV/256,  256, 0, stream>>>(hs, latkeys, counter, nbr);
  k_find      <<<NV/256,  256, 0, stream>>>(hs, hslot, pidx, cnt);
  k_scan1     <<<NBLK,   1024, 0, stream>>>(cnt, off, bsum);
  k_scan2     <<<1,      1024, 0, stream>>>(bsum);
  k_scan3     <<<NBLK,   1024, 0, stream>>>(off, bsum, cur);
  k_scatter   <<<NV/256,  256, 0, stream>>>(pidx, pbary, cur, plist2);
  k_splat2    <<<NV/256,  256, 0, stream>>>(xt, off, cnt, plist2, counter, latA);

  // 6 blur passes, ping-pong latA <-> latB, using precomputed neighbor lists
  __half* src = latA; __half* dst = latB;
  for (int j=0;j<6;j++){
    k_blur<<<NV/256, 256, 0, stream>>>(nbr + (size_t)j*NV, counter, src, dst);
    __half* tmp = src; src = dst; dst = tmp;
  }
  // after 6 swaps src == latA (final)
  k_slice<<<NPT/256, 256, 0, stream>>>(src, pidx, pbary, out);
}